// Round 7
// baseline (172.703 us; speedup 1.0000x reference)
//
#include <hip/hip_runtime.h>
#include <hip/hip_cooperative_groups.h>
#include <math.h>

namespace cg = cooperative_groups;

#define BB 64
#define NN 64
#define NM1 63
#define RR (NN*(NN-1))

// workspace layout (bytes)
#define WS1_OFF 0              // W1c B-frags: 16 tiles * 64 * 16B = 16 KB
#define WS2_OFF 16384          // W2 B-frags: 8 nt * 8 kc * 64 * 16B = 64 KB
#define WS3_OFF 81920          // W3 B-frags: 16 nt * 5 kc * 64 * 16B = 80 KB

typedef short bf16x8 __attribute__((ext_vector_type(8)));
typedef float f32x4 __attribute__((ext_vector_type(4)));
union U4 { uint4 u; bf16x8 b; };

__device__ inline unsigned int f2bf(float f) {
    unsigned int u = __float_as_uint(f);
    return (u + 0x7FFFu + ((u >> 16) & 1u)) >> 16;   // RNE fp32->bf16
}
__device__ inline unsigned int pack2(float a, float b) {
    return f2bf(a) | (f2bf(b) << 16);
}

// ---- weight fragment pack: entry e in [0,10240) -> one 16B bf16 frag ----
__device__ inline void pack_entry(int e,
    const float* __restrict__ W1, const float* __restrict__ W2,
    const float* __restrict__ W3, unsigned char* __restrict__ ws)
{
    const int u = e >> 6, l = e & 63;
    const int c16 = l & 15, qd = l >> 4;
    float v[8];
    uint4* dst;
    if (u < 16) {
        // W1 compact rows: kc<12 -> orig kc; 12..21 -> +10 (sender shape);
        // 22..31 -> -10 (receiver shape)
        const int nt = u, col = nt*16 + c16;
        #pragma unroll
        for (int j = 0; j < 8; ++j) {
            const int k = qd*8 + j;
            const int orig = k < 12 ? k : (k < 22 ? k+10 : k-10);
            v[j] = W1[orig*256 + col];
        }
        dst = (uint4*)(ws + WS1_OFF) + (nt*64 + l);
    } else if (u < 80) {
        const int w = u-16, nt = w >> 3, kc = w & 7, col = nt*16 + c16;
        #pragma unroll
        for (int j = 0; j < 8; ++j)
            v[j] = W2[(size_t)(kc*32 + qd*8 + j)*128 + col];
        dst = (uint4*)(ws + WS2_OFF) + ((nt*8 + kc)*64 + l);
    } else {
        const int w = u-80, nt = w/5, kc = w - nt*5, col = nt*16 + c16;
        #pragma unroll
        for (int j = 0; j < 8; ++j) {
            const int k = kc*32 + qd*8 + j;
            v[j] = (k < 141) ? W3[(size_t)k*256 + col] : 0.f;  // zero K-pad
        }
        dst = (uint4*)(ws + WS3_OFF) + ((nt*5 + kc)*64 + l);
    }
    uint4 o;
    o.x = pack2(v[0], v[1]); o.y = pack2(v[2], v[3]);
    o.z = pack2(v[4], v[5]); o.w = pack2(v[6], v[7]);
    *dst = o;
}

// ============ fallback prep (only used if cooperative launch fails) ========
__global__ __launch_bounds__(256) void prep_kernel(
    const float* __restrict__ W1, const float* __restrict__ W2,
    const float* __restrict__ W3, unsigned char* __restrict__ ws)
{
    const int e = blockIdx.x*256 + threadIdx.x;   // 40*256 = 10240 entries
    pack_entry(e, W1, W2, W3, ws);
}

// ============ main: G=8 receivers/block, 512 threads, grid B*8 ============
// COOP=true: single cooperative kernel. Threads t<20 pack 20 weight frags
// (transient regs, spill-safe), phases 0-1 run (no ws dependency) while the
// stores drain, grid.sync() makes ws visible device-wide (agent-scope fences
// in CG sync handle cross-XCD L2), then phases 2-5 stream packed weights.
// COOP=false: identical to the round-6 two-kernel path (prep ran before).
template<bool COOP>
__global__ __launch_bounds__(512) void main_kernel(
    const float* __restrict__ objects_state,
    const float* __restrict__ objects_shape,
    const float* __restrict__ relation_info,
    const float* __restrict__ s_mean, const float* __restrict__ s_std,
    const float* __restrict__ sh_mean, const float* __restrict__ sh_std,
    const float* __restrict__ v_mean, const float* __restrict__ v_std,
    const float* __restrict__ W1, const float* __restrict__ b1,
    const float* __restrict__ W2, const float* __restrict__ b2,
    const float* __restrict__ W3, const float* __restrict__ b3,
    const float* __restrict__ W4, const float* __restrict__ b4,
    unsigned char* __restrict__ ws,
    float* __restrict__ out)
{
    __shared__ __align__(16) float P[64][29];                 // 7424 B (29: bank-coprime)
    __shared__ __align__(16) unsigned int relb_w[8*64*16];    // 32768 B (row=64B)
    __shared__ __align__(16) unsigned short s_h[16*264];      // 8448 B
    __shared__ __align__(16) unsigned short s_q[16*168];      // 5376 B
    __shared__ int   s_cntg[8];
    __shared__ float s_red[8][16][3];
    __shared__ float s_outv[16][3];

    const int b  = blockIdx.x >> 3;
    const int nb = (blockIdx.x & 7) * 8;
    const int t  = threadIdx.x;
    const int wv = t >> 6, lane = t & 63, col16 = lane & 15, quad = lane >> 4;

    // ---- weight packing (coop only): 20 entries/block, issued first so the
    // stores drain under phases 0-1 ----
    if (COOP) {
        if (t < 20) pack_entry(blockIdx.x*20 + t, W1, W2, W3, ws);
    }

    // ---- relation_info direct read (wave wv owns group wv, lane = cand) ----
    float ri0 = 0.f, ri1 = 0.f, ri2 = 0.f;
    if (lane < 63) {
        const float* rp = relation_info
            + ((size_t)b*RR + (size_t)(nb + wv)*NM1 + lane)*3;
        ri0 = rp[0]; ri1 = rp[1]; ri2 = rp[2];
    }

    // ---- epilogue scalar prefetch (t<48 only; 7 regs) ----
    float e_vs0=0.f,e_vs1=0.f,e_vs2=0.f,e_vm0=0.f,e_vm1=0.f,e_vm2=0.f,e_b4=0.f;
    if (t < 48) {
        e_vs0 = v_std[0]; e_vs1 = v_std[1]; e_vs2 = v_std[2];
        e_vm0 = v_mean[0]; e_vm1 = v_mean[1]; e_vm2 = v_mean[2];
        e_b4  = b4[t % 3];
    }

    // ---- Phase 0: zero-init + per-object record compute ----
    // Per-object record: [0]=st0 [1]=st1 [2..9]=nst [10..19]=nsh
    // [20]=cos(nst2) [21]=sin(nst2) [22]=cos(st2) [23]=sin(st2)
    // [24]=vrot0 [25]=vrot1 [26]=st2raw [27..28]=pad
    {
        uint4 z = make_uint4(0,0,0,0);
        uint4* relb4 = (uint4*)relb_w;
        #pragma unroll
        for (int r = 0; r < 4; ++r) relb4[r*512 + t] = z;
        if (t < 336) ((uint4*)s_q)[t] = z;
        if (t < 64) {
            const int n = b*64 + t;
            const float4* sp4 = (const float4*)(objects_state + (size_t)n*8);
            const float4 sA = sp4[0], sB = sp4[1];
            float st[8] = {sA.x, sA.y, sA.z, sA.w, sB.x, sB.y, sB.z, sB.w};
            const float2* hp2 = (const float2*)(objects_shape + (size_t)n*10);
            float sh[10];
            #pragma unroll
            for (int c = 0; c < 5; ++c) {
                const float2 v = hp2[c];
                sh[c*2] = v.x; sh[c*2+1] = v.y;
            }
            float f[28];
            f[0] = st[0]; f[1] = st[1]; f[26] = st[2]; f[27] = 0.f;
            #pragma unroll
            for (int c = 0; c < 8; ++c)  f[2+c]  = (st[c] - s_mean[c]) / s_std[c];
            #pragma unroll
            for (int c = 0; c < 10; ++c) f[10+c] = (sh[c] - sh_mean[c]) / sh_std[c];
            // libm sinf/cosf to match reference precision
            const float sa = sinf(f[4]), ca = cosf(f[4]);
            const float sr = sinf(st[2]), cr = cosf(st[2]);
            f[20] = ca; f[21] = sa; f[22] = cr; f[23] = sr;
            f[24] =  ca*f[5] + sa*f[6];
            f[25] = -sa*f[5] + ca*f[6];
            #pragma unroll
            for (int c = 0; c < 28; ++c) P[t][c] = f[c];
        }
    }
    __syncthreads();

    // ---- Phase 1: build relation rows. wave wv == group, lane == candidate.
    // Slots via ballot prefix (no LDS atomics); P[n] reads are broadcast.
    // relb_w row = 64B = 4x16B chunks; chunk' = chunk ^ ((row>>1)&3).
    {
        const int g = wv, n = nb + g;
        bool pred = false;
        int j = 0;
        if (lane < 63) {
            j = lane + (lane >= n);
            const float dx = P[n][0] - P[j][0];
            const float dy = P[n][1] - P[j][1];
            const float dist = sqrtf(dx*dx + dy*dy);
            pred = (dist < 0.35f) && (dist != 0.0f);
        }
        const unsigned long long mask = __ballot(pred);
        if (lane == 0) s_cntg[g] = __popcll(mask);
        if (pred) {
            const int slot = __popcll(mask & ((1ull << lane) - 1ull));
            const int row = (g << 6) + slot;
            const int sw = (row >> 1) & 3;
            float f[32];
            f[0] = ri0; f[1] = ri1; f[2] = ri2;
            const float ca = P[n][20], sa = P[n][21];
            const float d0 = P[j][2]-P[n][2], d1 = P[j][3]-P[n][3];
            const float d2 = P[j][4]-P[n][4], d3 = P[j][5]-P[n][5];
            const float d4 = P[j][6]-P[n][6], d5 = P[j][7]-P[n][7];
            f[3]  =  ca*d0 + sa*d1;
            f[4]  = -sa*d0 + ca*d1;
            f[5]  =  ca*d3 + sa*d4;
            f[6]  = -sa*d3 + ca*d4;
            f[7]  =  ca*P[j][8] + sa*P[j][9];
            f[8]  = -sa*P[j][8] + ca*P[j][9];
            f[9]  = sinf(2.f*d2);
            f[10] = cosf(2.f*d2);
            f[11] = d5;
            #pragma unroll
            for (int c = 0; c < 10; ++c) f[12+c] = P[j][10+c];   // sender shape
            #pragma unroll
            for (int c = 0; c < 10; ++c) f[22+c] = P[n][10+c];   // receiver shape
            uint4* dst = (uint4*)&relb_w[row*16];
            #pragma unroll
            for (int w4 = 0; w4 < 4; ++w4) {
                uint4 o;
                o.x = pack2(f[w4*8+0], f[w4*8+1]);
                o.y = pack2(f[w4*8+2], f[w4*8+3]);
                o.z = pack2(f[w4*8+4], f[w4*8+5]);
                o.w = pack2(f[w4*8+6], f[w4*8+7]);
                dst[w4 ^ sw] = o;
            }
        }
    }
    __syncthreads();

    // ---- grid-wide sync: packed weights become visible device-wide ----
    if (COOP) cg::this_grid().sync();

    // ---- W1 B-frags + b1 (ws ready; short exposure before first MFMA) ----
    U4 bu0, bu1;
    {
        const uint4* w1f = (const uint4*)(ws + WS1_OFF);
        bu0.u = w1f[(wv*2+0)*64 + lane];
        bu1.u = w1f[(wv*2+1)*64 + lane];
    }
    const float b10 = b1[(wv*2+0)*16 + col16];
    const float b11 = b1[(wv*2+1)*16 + col16];

    // per-thread read swizzle for A-frags: (row>>1)&3 == (col16>>1)&3 since
    // row = 16*m + col16 with m*16 aligned
    const int rd_sw = (quad ^ ((col16 >> 1) & 3)) * 4;

    // ---- Phase 2: MLP1 MFMA (per wave: 2 N-tiles over 8 groups) ----
    {
        int cg_[8];
        #pragma unroll
        for (int g = 0; g < 8; ++g) cg_[g] = s_cntg[g];
        float hs0[8], hs1[8];
        #pragma unroll
        for (int g = 0; g < 8; ++g) { hs0[g] = 0.f; hs1[g] = 0.f; }
        #pragma unroll
        for (int g = 0; g < 8; ++g) {
            const int mts = (cg_[g] + 15) >> 4;
            for (int mt = 0; mt < mts; ++mt) {
                U4 au;
                au.u = *(const uint4*)&relb_w[((g<<6) + mt*16 + col16)*16 + rd_sw];
                f32x4 a0 = {0.f,0.f,0.f,0.f}, a1 = {0.f,0.f,0.f,0.f};
                a0 = __builtin_amdgcn_mfma_f32_16x16x32_bf16(au.b, bu0.b, a0, 0,0,0);
                a1 = __builtin_amdgcn_mfma_f32_16x16x32_bf16(au.b, bu1.b, a1, 0,0,0);
                #pragma unroll
                for (int i = 0; i < 4; ++i) {
                    hs0[g] += fmaxf(a0[i] + b10, 0.f);
                    hs1[g] += fmaxf(a1[i] + b11, 0.f);
                }
            }
        }
        // zero pad rows each contributed relu(b1); subtract them post-hoc
        const float rb0 = fmaxf(b10, 0.f), rb1 = fmaxf(b11, 0.f);
        #pragma unroll
        for (int g = 0; g < 8; ++g) {
            const int mts = (cg_[g] + 15) >> 4;
            const float pad = (float)(mts*16 - cg_[g]);
            float v0 = hs0[g], v1 = hs1[g];
            v0 += __shfl_xor(v0, 16); v0 += __shfl_xor(v0, 32);
            v1 += __shfl_xor(v1, 16); v1 += __shfl_xor(v1, 32);
            if (quad == 0) {
                s_h[g*264 + (wv*2+0)*16 + col16] =
                    (unsigned short)f2bf(v0 - pad*rb0);
                s_h[g*264 + (wv*2+1)*16 + col16] =
                    (unsigned short)f2bf(v1 - pad*rb1);
            }
        }
    }
    __syncthreads();

    // ---- Phase 3: obj_data q[0..12] + W2 GEMM -> q[13..140] ----
    if (t < 104) {
        const int m = t/13, c = t - m*13, n = nb + m;
        float v;
        if (c == 0) v = P[n][24];
        else if (c == 1) v = P[n][25];
        else if (c == 2) v = P[n][7];
        else v = P[n][10 + c - 3];
        s_q[m*168 + c] = (unsigned short)f2bf(v);
    }
    {
        U4 af[8];
        #pragma unroll
        for (int kc = 0; kc < 8; ++kc)
            af[kc].u = *(const uint4*)&s_h[(lane & 15)*264 + kc*32 + quad*8];
        float cntv[4];
        #pragma unroll
        for (int i = 0; i < 4; ++i)
            cntv[i] = (float)s_cntg[(quad*4 + i) & 7];
        const uint4* w2f = (const uint4*)(ws + WS2_OFF);
        f32x4 acc = {0.f,0.f,0.f,0.f};
        #pragma unroll
        for (int kc = 0; kc < 8; ++kc) {
            U4 bu; bu.u = w2f[(wv*8 + kc)*64 + lane];
            acc = __builtin_amdgcn_mfma_f32_16x16x32_bf16(af[kc].b, bu.b, acc, 0,0,0);
        }
        const float b2v = b2[wv*16 + col16];
        #pragma unroll
        for (int i = 0; i < 4; ++i) {
            const int row = quad*4 + i;
            s_q[row*168 + 13 + wv*16 + col16] =
                (unsigned short)f2bf(acc[i] + cntv[i]*b2v);
        }
    }
    __syncthreads();

    // ---- Phase 4: W3 GEMM + relu + W4 partials ----
    {
        U4 af3[5];
        #pragma unroll
        for (int kc = 0; kc < 5; ++kc)
            af3[kc].u = *(const uint4*)&s_q[(lane & 15)*168 + kc*32 + quad*8];
        const uint4* w3f = (const uint4*)(ws + WS3_OFF);
        float p[4][3];
        #pragma unroll
        for (int i = 0; i < 4; ++i) { p[i][0]=0.f; p[i][1]=0.f; p[i][2]=0.f; }
        #pragma unroll
        for (int ntl = 0; ntl < 2; ++ntl) {
            const int nt = wv + ntl*8, col = nt*16 + col16;
            f32x4 acc = {0.f,0.f,0.f,0.f};
            #pragma unroll
            for (int kc = 0; kc < 5; ++kc) {
                U4 bu; bu.u = w3f[(nt*5 + kc)*64 + lane];
                acc = __builtin_amdgcn_mfma_f32_16x16x32_bf16(af3[kc].b, bu.b, acc, 0,0,0);
            }
            const float b3v = b3[col];
            const float w40 = W4[col*3+0], w41 = W4[col*3+1], w42 = W4[col*3+2];
            #pragma unroll
            for (int i = 0; i < 4; ++i) {
                const float h = fmaxf(acc[i] + b3v, 0.f);
                p[i][0] = fmaf(h, w40, p[i][0]);
                p[i][1] = fmaf(h, w41, p[i][1]);
                p[i][2] = fmaf(h, w42, p[i][2]);
            }
        }
        #pragma unroll
        for (int off = 1; off < 16; off <<= 1)
            #pragma unroll
            for (int i = 0; i < 4; ++i) {
                p[i][0] += __shfl_xor(p[i][0], off);
                p[i][1] += __shfl_xor(p[i][1], off);
                p[i][2] += __shfl_xor(p[i][2], off);
            }
        if (col16 == 0)
            #pragma unroll
            for (int i = 0; i < 4; ++i) {
                s_red[wv][quad*4+i][0] = p[i][0];
                s_red[wv][quad*4+i][1] = p[i][1];
                s_red[wv][quad*4+i][2] = p[i][2];
            }
    }
    __syncthreads();
    if (t < 48) {
        const int m = t/3, o = t - m*3;
        float acc = e_b4;   // b4[o] prefetched (o == t%3)
        #pragma unroll
        for (int w = 0; w < 8; ++w) acc += s_red[w][m][o];
        s_outv[m][o] = acc;
    }
    __syncthreads();

    // ---- Phase 5: epilogue (scalars prefetched at kernel top) ----
    if (t < 48) {
        const int m = t/6, i = t - m*6, n = nb + m;
        if (n >= 1) {
            const float q0 = s_outv[m][0]*e_vs0 + e_vm0;
            const float q1 = s_outv[m][1]*e_vs1 + e_vm1;
            const float q2 = s_outv[m][2]*e_vs2 + e_vm2;
            const float cr = P[n][22], sr = P[n][23];
            const float xd0 = cr*q0 - sr*q1;
            const float xd1 = sr*q0 + cr*q1;
            const int im = i % 3;
            const float xd = (im == 0) ? xd0 : (im == 1) ? xd1 : q2;
            float base = 0.f;
            if (i == 0) base = P[n][0];
            else if (i == 1) base = P[n][1];
            else if (i == 2) base = P[n][26];
            out[((size_t)b*NM1 + (n-1))*6 + i] = base + xd;
        }
    }
}

extern "C" void kernel_launch(void* const* d_in, const int* in_sizes, int n_in,
                              void* d_out, int out_size, void* d_ws, size_t ws_size,
                              hipStream_t stream) {
    const float* objects_state = (const float*)d_in[0];
    const float* objects_shape = (const float*)d_in[1];
    const float* relation_info = (const float*)d_in[2];
    const float* s_mean  = (const float*)d_in[3];
    const float* s_std   = (const float*)d_in[4];
    const float* sh_mean = (const float*)d_in[5];
    const float* sh_std  = (const float*)d_in[6];
    const float* v_mean  = (const float*)d_in[7];
    const float* v_std   = (const float*)d_in[8];
    const float* W1 = (const float*)d_in[9];
    const float* b1 = (const float*)d_in[10];
    const float* W2 = (const float*)d_in[11];
    const float* b2 = (const float*)d_in[12];
    const float* W3 = (const float*)d_in[13];
    const float* b3 = (const float*)d_in[14];
    const float* W4 = (const float*)d_in[15];
    const float* b4 = (const float*)d_in[16];
    unsigned char* ws = (unsigned char*)d_ws;
    float* outp = (float*)d_out;
    (void)in_sizes; (void)n_in; (void)out_size; (void)ws_size;

    void* args[] = {
        (void*)&objects_state, (void*)&objects_shape, (void*)&relation_info,
        (void*)&s_mean, (void*)&s_std, (void*)&sh_mean, (void*)&sh_std,
        (void*)&v_mean, (void*)&v_std,
        (void*)&W1, (void*)&b1, (void*)&W2, (void*)&b2,
        (void*)&W3, (void*)&b3, (void*)&W4, (void*)&b4,
        (void*)&ws, (void*)&outp
    };
    hipError_t err = hipLaunchCooperativeKernel(
        (const void*)main_kernel<true>, dim3(BB*8), dim3(512), args, 0, stream);
    if (err != hipSuccess) {
        // fallback: round-6 two-kernel path
        prep_kernel<<<dim3(40), dim3(256), 0, stream>>>(W1, W2, W3, ws);
        main_kernel<false><<<dim3(BB*8), dim3(512), 0, stream>>>(
            objects_state, objects_shape, relation_info,
            s_mean, s_std, sh_mean, sh_std, v_mean, v_std,
            W1, b1, W2, b2, W3, b3, W4, b4, ws, outp);
    }
}

// Round 8
// 104.540 us; speedup vs baseline: 1.6520x; 1.6520x over previous
//
#include <hip/hip_runtime.h>
#include <math.h>

#define BB 64
#define NN 64
#define NM1 63
#define RR (NN*(NN-1))

// workspace layout (bytes)
#define WS1_OFF 0              // W1c B-frags: 16 tiles * 64 * 16B = 16 KB
#define WS2_OFF 16384          // W2 B-frags: 8 nt * 8 kc * 64 * 16B = 64 KB
#define WS3_OFF 81920          // W3 B-frags: 16 nt * 5 kc * 64 * 16B = 80 KB

typedef short bf16x8 __attribute__((ext_vector_type(8)));
typedef float f32x4 __attribute__((ext_vector_type(4)));
union U4 { uint4 u; bf16x8 b; };

__device__ inline unsigned int f2bf(float f) {
    unsigned int u = __float_as_uint(f);
    return (u + 0x7FFFu + ((u >> 16) & 1u)) >> 16;   // RNE fp32->bf16
}
__device__ inline unsigned int pack2(float a, float b) {
    return f2bf(a) | (f2bf(b) << 16);
}

// ============ prep: weight pack only (40 blocks) ============
// Measured-best structure (round 6, 104.1 us total). Alternatives bracketed:
// single fused kernel +3.5us (weight reload latency); cooperative merge
// +68us (grid.sync costs ~20us at 512 blocks on MI355X); in-register f32
// staging spills 46-82MB at the compiler's 64-VGPR target.
__global__ __launch_bounds__(256) void prep_kernel(
    const float* __restrict__ W1, const float* __restrict__ W2,
    const float* __restrict__ W3, unsigned char* __restrict__ ws)
{
    const int t = threadIdx.x;
    const int u = blockIdx.x*4 + (t >> 6), l = t & 63;
    const int col16 = l & 15, quad = l >> 4;
    float v[8];
    uint4* dst;
    if (u < 16) {
        // W1 compact rows: kc<12 -> orig kc; 12..21 -> orig kc+10 (sender
        // shape); 22..31 -> orig kc-10 (receiver shape)
        const int nt = u, col = nt*16 + col16;
        #pragma unroll
        for (int j = 0; j < 8; ++j) {
            const int k = quad*8 + j;
            const int orig = k < 12 ? k : (k < 22 ? k+10 : k-10);
            v[j] = W1[orig*256 + col];
        }
        dst = (uint4*)(ws + WS1_OFF) + (nt*64 + l);
    } else if (u < 80) {
        const int w = u-16, nt = w >> 3, kc = w & 7, col = nt*16 + col16;
        #pragma unroll
        for (int j = 0; j < 8; ++j)
            v[j] = W2[(size_t)(kc*32 + quad*8 + j)*128 + col];
        dst = (uint4*)(ws + WS2_OFF) + ((nt*8 + kc)*64 + l);
    } else {
        const int w = u-80, nt = w/5, kc = w - nt*5, col = nt*16 + col16;
        #pragma unroll
        for (int j = 0; j < 8; ++j) {
            const int k = kc*32 + quad*8 + j;
            v[j] = (k < 141) ? W3[(size_t)k*256 + col] : 0.f;  // zero K-pad
        }
        dst = (uint4*)(ws + WS3_OFF) + ((nt*5 + kc)*64 + l);
    }
    uint4 o;
    o.x = pack2(v[0], v[1]); o.y = pack2(v[2], v[3]);
    o.z = pack2(v[4], v[5]); o.w = pack2(v[6], v[7]);
    *dst = o;
}

// ============ main: G=8 receivers/block, 512 threads, grid B*8 ============
// Streams pre-packed bf16 weights from ws (transient regs, no staging ->
// spill-free). Ballot-based phase 1 (wave==group, no LDS atomics), in-block
// P compute, relb_w 16B-chunk XOR swizzle (A-frag reads were 8-way:
// 596K->285K measured), P stride 29 (bank-coprime).
__global__ __launch_bounds__(512) void main_kernel(
    const float* __restrict__ objects_state,
    const float* __restrict__ objects_shape,
    const float* __restrict__ relation_info,
    const float* __restrict__ s_mean, const float* __restrict__ s_std,
    const float* __restrict__ sh_mean, const float* __restrict__ sh_std,
    const float* __restrict__ v_mean, const float* __restrict__ v_std,
    const float* __restrict__ b1, const float* __restrict__ b2,
    const float* __restrict__ b3,
    const float* __restrict__ W4, const float* __restrict__ b4,
    const unsigned char* __restrict__ ws,
    float* __restrict__ out)
{
    __shared__ __align__(16) float P[64][29];                 // 7424 B (29: bank-coprime)
    __shared__ __align__(16) unsigned int relb_w[8*64*16];    // 32768 B (row=64B)
    __shared__ __align__(16) unsigned short s_h[16*264];      // 8448 B
    __shared__ __align__(16) unsigned short s_q[16*168];      // 5376 B
    __shared__ int   s_cntg[8];
    __shared__ float s_red[8][16][3];
    __shared__ float s_outv[16][3];

    const int b  = blockIdx.x >> 3;
    const int nb = (blockIdx.x & 7) * 8;
    const int t  = threadIdx.x;
    const int wv = t >> 6, lane = t & 63, col16 = lane & 15, quad = lane >> 4;

    // ---- W1 B-frags + b1: hoisted to top (prep finished via stream order;
    // latency hides under phase 0/1) ----
    U4 bu0, bu1;
    {
        const uint4* w1f = (const uint4*)(ws + WS1_OFF);
        bu0.u = w1f[(wv*2+0)*64 + lane];
        bu1.u = w1f[(wv*2+1)*64 + lane];
    }
    const float b10 = b1[(wv*2+0)*16 + col16];
    const float b11 = b1[(wv*2+1)*16 + col16];

    // ---- relation_info direct read (wave wv owns group wv, lane = cand) ----
    float ri0 = 0.f, ri1 = 0.f, ri2 = 0.f;
    if (lane < 63) {
        const float* rp = relation_info
            + ((size_t)b*RR + (size_t)(nb + wv)*NM1 + lane)*3;
        ri0 = rp[0]; ri1 = rp[1]; ri2 = rp[2];
    }

    // ---- epilogue scalar prefetch (t<48 only; 7 regs) ----
    float e_vs0=0.f,e_vs1=0.f,e_vs2=0.f,e_vm0=0.f,e_vm1=0.f,e_vm2=0.f,e_b4=0.f;
    if (t < 48) {
        e_vs0 = v_std[0]; e_vs1 = v_std[1]; e_vs2 = v_std[2];
        e_vm0 = v_mean[0]; e_vm1 = v_mean[1]; e_vm2 = v_mean[2];
        e_b4  = b4[t % 3];
    }

    // ---- Phase 0: zero-init + per-object record compute ----
    // Per-object record: [0]=st0 [1]=st1 [2..9]=nst [10..19]=nsh
    // [20]=cos(nst2) [21]=sin(nst2) [22]=cos(st2) [23]=sin(st2)
    // [24]=vrot0 [25]=vrot1 [26]=st2raw [27..28]=pad
    {
        uint4 z = make_uint4(0,0,0,0);
        uint4* relb4 = (uint4*)relb_w;
        #pragma unroll
        for (int r = 0; r < 4; ++r) relb4[r*512 + t] = z;
        if (t < 336) ((uint4*)s_q)[t] = z;
        if (t < 64) {
            const int n = b*64 + t;
            const float4* sp4 = (const float4*)(objects_state + (size_t)n*8);
            const float4 sA = sp4[0], sB = sp4[1];
            float st[8] = {sA.x, sA.y, sA.z, sA.w, sB.x, sB.y, sB.z, sB.w};
            const float2* hp2 = (const float2*)(objects_shape + (size_t)n*10);
            float sh[10];
            #pragma unroll
            for (int c = 0; c < 5; ++c) {
                const float2 v = hp2[c];
                sh[c*2] = v.x; sh[c*2+1] = v.y;
            }
            float f[28];
            f[0] = st[0]; f[1] = st[1]; f[26] = st[2]; f[27] = 0.f;
            #pragma unroll
            for (int c = 0; c < 8; ++c)  f[2+c]  = (st[c] - s_mean[c]) / s_std[c];
            #pragma unroll
            for (int c = 0; c < 10; ++c) f[10+c] = (sh[c] - sh_mean[c]) / sh_std[c];
            // libm sinf/cosf to match reference precision
            const float sa = sinf(f[4]), ca = cosf(f[4]);
            const float sr = sinf(st[2]), cr = cosf(st[2]);
            f[20] = ca; f[21] = sa; f[22] = cr; f[23] = sr;
            f[24] =  ca*f[5] + sa*f[6];
            f[25] = -sa*f[5] + ca*f[6];
            #pragma unroll
            for (int c = 0; c < 28; ++c) P[t][c] = f[c];
        }
    }
    __syncthreads();

    // ---- Phase 1: build relation rows. wave wv == group, lane == candidate.
    // Slots via ballot prefix (no LDS atomics); P[n] reads are broadcast.
    // relb_w row = 64B = 4x16B chunks; chunk' = chunk ^ ((row>>1)&3).
    {
        const int g = wv, n = nb + g;
        bool pred = false;
        int j = 0;
        if (lane < 63) {
            j = lane + (lane >= n);
            const float dx = P[n][0] - P[j][0];
            const float dy = P[n][1] - P[j][1];
            const float dist = sqrtf(dx*dx + dy*dy);
            pred = (dist < 0.35f) && (dist != 0.0f);
        }
        const unsigned long long mask = __ballot(pred);
        if (lane == 0) s_cntg[g] = __popcll(mask);
        if (pred) {
            const int slot = __popcll(mask & ((1ull << lane) - 1ull));
            const int row = (g << 6) + slot;
            const int sw = (row >> 1) & 3;
            float f[32];
            f[0] = ri0; f[1] = ri1; f[2] = ri2;
            const float ca = P[n][20], sa = P[n][21];
            const float d0 = P[j][2]-P[n][2], d1 = P[j][3]-P[n][3];
            const float d2 = P[j][4]-P[n][4], d3 = P[j][5]-P[n][5];
            const float d4 = P[j][6]-P[n][6], d5 = P[j][7]-P[n][7];
            f[3]  =  ca*d0 + sa*d1;
            f[4]  = -sa*d0 + ca*d1;
            f[5]  =  ca*d3 + sa*d4;
            f[6]  = -sa*d3 + ca*d4;
            f[7]  =  ca*P[j][8] + sa*P[j][9];
            f[8]  = -sa*P[j][8] + ca*P[j][9];
            f[9]  = sinf(2.f*d2);
            f[10] = cosf(2.f*d2);
            f[11] = d5;
            #pragma unroll
            for (int c = 0; c < 10; ++c) f[12+c] = P[j][10+c];   // sender shape
            #pragma unroll
            for (int c = 0; c < 10; ++c) f[22+c] = P[n][10+c];   // receiver shape
            uint4* dst = (uint4*)&relb_w[row*16];
            #pragma unroll
            for (int w4 = 0; w4 < 4; ++w4) {
                uint4 o;
                o.x = pack2(f[w4*8+0], f[w4*8+1]);
                o.y = pack2(f[w4*8+2], f[w4*8+3]);
                o.z = pack2(f[w4*8+4], f[w4*8+5]);
                o.w = pack2(f[w4*8+6], f[w4*8+7]);
                dst[w4 ^ sw] = o;
            }
        }
    }
    __syncthreads();

    // per-thread read swizzle for A-frags: (row>>1)&3 == (col16>>1)&3 since
    // row = 16*m + col16 with m*16 aligned
    const int rd_sw = (quad ^ ((col16 >> 1) & 3)) * 4;

    // ---- Phase 2: MLP1 MFMA (per wave: 2 N-tiles over 8 groups) ----
    {
        int cg[8];
        #pragma unroll
        for (int g = 0; g < 8; ++g) cg[g] = s_cntg[g];
        float hs0[8], hs1[8];
        #pragma unroll
        for (int g = 0; g < 8; ++g) { hs0[g] = 0.f; hs1[g] = 0.f; }
        #pragma unroll
        for (int g = 0; g < 8; ++g) {
            const int mts = (cg[g] + 15) >> 4;
            for (int mt = 0; mt < mts; ++mt) {
                U4 au;
                au.u = *(const uint4*)&relb_w[((g<<6) + mt*16 + col16)*16 + rd_sw];
                f32x4 a0 = {0.f,0.f,0.f,0.f}, a1 = {0.f,0.f,0.f,0.f};
                a0 = __builtin_amdgcn_mfma_f32_16x16x32_bf16(au.b, bu0.b, a0, 0,0,0);
                a1 = __builtin_amdgcn_mfma_f32_16x16x32_bf16(au.b, bu1.b, a1, 0,0,0);
                #pragma unroll
                for (int i = 0; i < 4; ++i) {
                    hs0[g] += fmaxf(a0[i] + b10, 0.f);
                    hs1[g] += fmaxf(a1[i] + b11, 0.f);
                }
            }
        }
        // zero pad rows each contributed relu(b1); subtract them post-hoc
        const float rb0 = fmaxf(b10, 0.f), rb1 = fmaxf(b11, 0.f);
        #pragma unroll
        for (int g = 0; g < 8; ++g) {
            const int mts = (cg[g] + 15) >> 4;
            const float pad = (float)(mts*16 - cg[g]);
            float v0 = hs0[g], v1 = hs1[g];
            v0 += __shfl_xor(v0, 16); v0 += __shfl_xor(v0, 32);
            v1 += __shfl_xor(v1, 16); v1 += __shfl_xor(v1, 32);
            if (quad == 0) {
                s_h[g*264 + (wv*2+0)*16 + col16] =
                    (unsigned short)f2bf(v0 - pad*rb0);
                s_h[g*264 + (wv*2+1)*16 + col16] =
                    (unsigned short)f2bf(v1 - pad*rb1);
            }
        }
    }
    __syncthreads();

    // ---- Phase 3: obj_data q[0..12] + W2 GEMM -> q[13..140] ----
    if (t < 104) {
        const int m = t/13, c = t - m*13, n = nb + m;
        float v;
        if (c == 0) v = P[n][24];
        else if (c == 1) v = P[n][25];
        else if (c == 2) v = P[n][7];
        else v = P[n][10 + c - 3];
        s_q[m*168 + c] = (unsigned short)f2bf(v);
    }
    {
        U4 af[8];
        #pragma unroll
        for (int kc = 0; kc < 8; ++kc)
            af[kc].u = *(const uint4*)&s_h[(lane & 15)*264 + kc*32 + quad*8];
        float cntv[4];
        #pragma unroll
        for (int i = 0; i < 4; ++i)
            cntv[i] = (float)s_cntg[(quad*4 + i) & 7];
        const uint4* w2f = (const uint4*)(ws + WS2_OFF);
        f32x4 acc = {0.f,0.f,0.f,0.f};
        #pragma unroll
        for (int kc = 0; kc < 8; ++kc) {
            U4 bu; bu.u = w2f[(wv*8 + kc)*64 + lane];
            acc = __builtin_amdgcn_mfma_f32_16x16x32_bf16(af[kc].b, bu.b, acc, 0,0,0);
        }
        const float b2v = b2[wv*16 + col16];
        #pragma unroll
        for (int i = 0; i < 4; ++i) {
            const int row = quad*4 + i;
            s_q[row*168 + 13 + wv*16 + col16] =
                (unsigned short)f2bf(acc[i] + cntv[i]*b2v);
        }
    }
    __syncthreads();

    // ---- Phase 4: W3 GEMM + relu + W4 partials ----
    {
        U4 af3[5];
        #pragma unroll
        for (int kc = 0; kc < 5; ++kc)
            af3[kc].u = *(const uint4*)&s_q[(lane & 15)*168 + kc*32 + quad*8];
        const uint4* w3f = (const uint4*)(ws + WS3_OFF);
        float p[4][3];
        #pragma unroll
        for (int i = 0; i < 4; ++i) { p[i][0]=0.f; p[i][1]=0.f; p[i][2]=0.f; }
        #pragma unroll
        for (int ntl = 0; ntl < 2; ++ntl) {
            const int nt = wv + ntl*8, col = nt*16 + col16;
            f32x4 acc = {0.f,0.f,0.f,0.f};
            #pragma unroll
            for (int kc = 0; kc < 5; ++kc) {
                U4 bu; bu.u = w3f[(nt*5 + kc)*64 + lane];
                acc = __builtin_amdgcn_mfma_f32_16x16x32_bf16(af3[kc].b, bu.b, acc, 0,0,0);
            }
            const float b3v = b3[col];
            const float w40 = W4[col*3+0], w41 = W4[col*3+1], w42 = W4[col*3+2];
            #pragma unroll
            for (int i = 0; i < 4; ++i) {
                const float h = fmaxf(acc[i] + b3v, 0.f);
                p[i][0] = fmaf(h, w40, p[i][0]);
                p[i][1] = fmaf(h, w41, p[i][1]);
                p[i][2] = fmaf(h, w42, p[i][2]);
            }
        }
        #pragma unroll
        for (int off = 1; off < 16; off <<= 1)
            #pragma unroll
            for (int i = 0; i < 4; ++i) {
                p[i][0] += __shfl_xor(p[i][0], off);
                p[i][1] += __shfl_xor(p[i][1], off);
                p[i][2] += __shfl_xor(p[i][2], off);
            }
        if (col16 == 0)
            #pragma unroll
            for (int i = 0; i < 4; ++i) {
                s_red[wv][quad*4+i][0] = p[i][0];
                s_red[wv][quad*4+i][1] = p[i][1];
                s_red[wv][quad*4+i][2] = p[i][2];
            }
    }
    __syncthreads();
    if (t < 48) {
        const int m = t/3, o = t - m*3;
        float acc = e_b4;   // b4[o] prefetched (o == t%3)
        #pragma unroll
        for (int w = 0; w < 8; ++w) acc += s_red[w][m][o];
        s_outv[m][o] = acc;
    }
    __syncthreads();

    // ---- Phase 5: epilogue (scalars prefetched at kernel top) ----
    if (t < 48) {
        const int m = t/6, i = t - m*6, n = nb + m;
        if (n >= 1) {
            const float q0 = s_outv[m][0]*e_vs0 + e_vm0;
            const float q1 = s_outv[m][1]*e_vs1 + e_vm1;
            const float q2 = s_outv[m][2]*e_vs2 + e_vm2;
            const float cr = P[n][22], sr = P[n][23];
            const float xd0 = cr*q0 - sr*q1;
            const float xd1 = sr*q0 + cr*q1;
            const int im = i % 3;
            const float xd = (im == 0) ? xd0 : (im == 1) ? xd1 : q2;
            float base = 0.f;
            if (i == 0) base = P[n][0];
            else if (i == 1) base = P[n][1];
            else if (i == 2) base = P[n][26];
            out[((size_t)b*NM1 + (n-1))*6 + i] = base + xd;
        }
    }
}

extern "C" void kernel_launch(void* const* d_in, const int* in_sizes, int n_in,
                              void* d_out, int out_size, void* d_ws, size_t ws_size,
                              hipStream_t stream) {
    const float* objects_state = (const float*)d_in[0];
    const float* objects_shape = (const float*)d_in[1];
    const float* relation_info = (const float*)d_in[2];
    const float* s_mean  = (const float*)d_in[3];
    const float* s_std   = (const float*)d_in[4];
    const float* sh_mean = (const float*)d_in[5];
    const float* sh_std  = (const float*)d_in[6];
    const float* v_mean  = (const float*)d_in[7];
    const float* v_std   = (const float*)d_in[8];
    const float* W1 = (const float*)d_in[9];
    const float* b1 = (const float*)d_in[10];
    const float* W2 = (const float*)d_in[11];
    const float* b2 = (const float*)d_in[12];
    const float* W3 = (const float*)d_in[13];
    const float* b3 = (const float*)d_in[14];
    const float* W4 = (const float*)d_in[15];
    const float* b4 = (const float*)d_in[16];
    unsigned char* ws = (unsigned char*)d_ws;

    prep_kernel<<<dim3(40), dim3(256), 0, stream>>>(W1, W2, W3, ws);
    main_kernel<<<dim3(BB*8), dim3(512), 0, stream>>>(
        objects_state, objects_shape, relation_info,
        s_mean, s_std, sh_mean, sh_std, v_mean, v_std,
        b1, b2, b3, W4, b4, ws, (float*)d_out);
}